// Round 1
// baseline (1050.575 us; speedup 1.0000x reference)
//
#include <hip/hip_runtime.h>
#include <hip/hip_bf16.h>

#define N_NODES 200000
#define N_EDGES 640000
#define D_NODE 128
#define D_EDGE 32
#define HIDDEN 128

using bf16x8  = __attribute__((ext_vector_type(8))) short;
using f32x4   = __attribute__((ext_vector_type(4))) float;
using short4v = __attribute__((ext_vector_type(4))) short;

__device__ __forceinline__ short f2b(float f) {
  return __builtin_bit_cast(short, __float2bfloat16(f));
}

// ---------------------------------------------------------------------------
// K1: edge GEMM  msg = [x[row], edge_attr] @ W1 + b1, atomic scatter to agg[col]
//   BM=128 edges/block, K=160, N=128. 4 waves in 2x2, each 64x64 output.
// ---------------------------------------------------------------------------
#define EBM 128
#define EK  160
#define ELD 168   // padded bf16 stride: 336B rows -> worst 2-way bank alias (free)

__global__ __launch_bounds__(256) void k_edge(
    const float* __restrict__ x, const int* __restrict__ ei,
    const float* __restrict__ ea, const float* __restrict__ W1,
    const float* __restrict__ b1, float* agg)
{
  __shared__ short lA[EBM * ELD];     // 43008 B  [edge][k]
  __shared__ short lB[HIDDEN * ELD];  // 43008 B  W1^T: [n][k]
  const int tid = threadIdx.x;
  const int e0  = blockIdx.x * EBM;

  // stage W1^T (160x128 f32 -> bf16, transposed)
  for (int i = tid; i < (EK * HIDDEN) / 4; i += 256) {   // 5120 float4
    const int k = i >> 5;            // 32 float4 per k-row
    const int n = (i & 31) << 2;
    const float4 v = *(const float4*)&W1[k * HIDDEN + n];
    lB[(n + 0) * ELD + k] = f2b(v.x);
    lB[(n + 1) * ELD + k] = f2b(v.y);
    lB[(n + 2) * ELD + k] = f2b(v.z);
    lB[(n + 3) * ELD + k] = f2b(v.w);
  }
  // stage A = [x[row] | edge_attr] as bf16
  for (int i = tid; i < EBM * 40; i += 256) {            // 40 float4 per edge row
    const int m = i / 40;
    const int q = i % 40;
    float4 v;
    if (q < 32) {
      const int r = ei[e0 + m];                          // source node
      v = *(const float4*)&x[(size_t)r * D_NODE + (q << 2)];
    } else {
      v = *(const float4*)&ea[(size_t)(e0 + m) * D_EDGE + ((q - 32) << 2)];
    }
    short4v s = { f2b(v.x), f2b(v.y), f2b(v.z), f2b(v.w) };
    *(short4v*)&lA[m * ELD + (q << 2)] = s;
  }
  __syncthreads();

  const int lane = tid & 63;
  const int wid  = tid >> 6;
  const int wm = wid >> 1, wn = wid & 1;
  const int lrow = lane & 15;
  const int lk   = (lane >> 4) << 3;

  f32x4 acc[4][4] = {};
  #pragma unroll
  for (int kt = 0; kt < 5; ++kt) {
    const int ks = kt * 32 + lk;
    bf16x8 af[4], bfr[4];
    #pragma unroll
    for (int i = 0; i < 4; ++i)
      af[i]  = *(const bf16x8*)&lA[(wm * 64 + i * 16 + lrow) * ELD + ks];
    #pragma unroll
    for (int j = 0; j < 4; ++j)
      bfr[j] = *(const bf16x8*)&lB[(wn * 64 + j * 16 + lrow) * ELD + ks];
    #pragma unroll
    for (int i = 0; i < 4; ++i)
      #pragma unroll
      for (int j = 0; j < 4; ++j)
        acc[i][j] = __builtin_amdgcn_mfma_f32_16x16x32_bf16(af[i], bfr[j], acc[i][j], 0, 0, 0);
  }

  // epilogue: +b1, atomic scatter to agg[col[e]]
  const int rb = wm * 64 + ((lane >> 4) << 2);
  const int cb = wn * 64 + lrow;
  #pragma unroll
  for (int j = 0; j < 4; ++j) {
    const int c = cb + j * 16;
    const float bias = b1[c];
    #pragma unroll
    for (int i = 0; i < 4; ++i) {
      #pragma unroll
      for (int r = 0; r < 4; ++r) {
        const int m    = rb + i * 16 + r;
        const int node = ei[N_EDGES + e0 + m];           // destination node
        unsafeAtomicAdd(&agg[(size_t)node * HIDDEN + c], acc[i][j][r] + bias);
      }
    }
  }
}

// ---------------------------------------------------------------------------
// K2: node GEMM  out = [x, agg] @ W2 + b2
//   BM=128 nodes/block, K=256, N=128. agg aliases out (d_out): each block reads
//   its own rows before the barrier and writes the same rows after -> safe.
// ---------------------------------------------------------------------------
#define NBM 128
#define NK  256
#define NLD 264

__global__ __launch_bounds__(256) void k_node(
    const float* __restrict__ x, const float* agg,
    const float* __restrict__ W2, const float* __restrict__ b2,
    float* out)
{
  __shared__ short lA[NBM * NLD];     // 67584 B
  __shared__ short lB[HIDDEN * NLD];  // 67584 B  W2^T: [n][k]
  const int tid = threadIdx.x;
  const int n0  = blockIdx.x * NBM;

  for (int i = tid; i < (NK * HIDDEN) / 4; i += 256) {   // 8192 float4
    const int k = i >> 5;
    const int n = (i & 31) << 2;
    const float4 v = *(const float4*)&W2[k * HIDDEN + n];
    lB[(n + 0) * NLD + k] = f2b(v.x);
    lB[(n + 1) * NLD + k] = f2b(v.y);
    lB[(n + 2) * NLD + k] = f2b(v.z);
    lB[(n + 3) * NLD + k] = f2b(v.w);
  }
  for (int i = tid; i < NBM * 64; i += 256) {            // 64 float4 per node row
    const int m = i >> 6, q = i & 63;
    int node = n0 + m;
    if (node >= N_NODES) node = N_NODES - 1;             // clamp (tail)
    const float* src = (q < 32) ? &x[(size_t)node * D_NODE + (q << 2)]
                                : &agg[(size_t)node * HIDDEN + ((q - 32) << 2)];
    const float4 v = *(const float4*)src;
    short4v s = { f2b(v.x), f2b(v.y), f2b(v.z), f2b(v.w) };
    *(short4v*)&lA[m * NLD + (q << 2)] = s;
  }
  __syncthreads();

  const int lane = tid & 63;
  const int wid  = tid >> 6;
  const int wm = wid >> 1, wn = wid & 1;
  const int lrow = lane & 15;
  const int lk   = (lane >> 4) << 3;

  f32x4 acc[4][4] = {};
  #pragma unroll
  for (int kt = 0; kt < 8; ++kt) {
    const int ks = kt * 32 + lk;
    bf16x8 af[4], bfr[4];
    #pragma unroll
    for (int i = 0; i < 4; ++i)
      af[i]  = *(const bf16x8*)&lA[(wm * 64 + i * 16 + lrow) * NLD + ks];
    #pragma unroll
    for (int j = 0; j < 4; ++j)
      bfr[j] = *(const bf16x8*)&lB[(wn * 64 + j * 16 + lrow) * NLD + ks];
    #pragma unroll
    for (int i = 0; i < 4; ++i)
      #pragma unroll
      for (int j = 0; j < 4; ++j)
        acc[i][j] = __builtin_amdgcn_mfma_f32_16x16x32_bf16(af[i], bfr[j], acc[i][j], 0, 0, 0);
  }

  const int rb = wm * 64 + ((lane >> 4) << 2);
  const int cb = wn * 64 + lrow;
  #pragma unroll
  for (int j = 0; j < 4; ++j) {
    const int c = cb + j * 16;
    const float bias = b2[c];
    #pragma unroll
    for (int i = 0; i < 4; ++i) {
      #pragma unroll
      for (int r = 0; r < 4; ++r) {
        const int m    = rb + i * 16 + r;
        const int node = n0 + m;
        if (node < N_NODES)
          out[(size_t)node * HIDDEN + c] = acc[i][j][r] + bias;
      }
    }
  }
}

extern "C" void kernel_launch(void* const* d_in, const int* in_sizes, int n_in,
                              void* d_out, int out_size, void* d_ws, size_t ws_size,
                              hipStream_t stream) {
  const float* x  = (const float*)d_in[0];
  const int*   ei = (const int*)d_in[1];
  const float* ea = (const float*)d_in[2];
  // d_in[3] = u, d_in[4] = batch : unused by the reference
  const float* W1 = (const float*)d_in[5];
  const float* b1 = (const float*)d_in[6];
  const float* W2 = (const float*)d_in[7];
  const float* b2 = (const float*)d_in[8];
  float* out = (float*)d_out;

  // d_out doubles as the f32 agg buffer for the scatter phase.
  hipMemsetAsync(out, 0, (size_t)N_NODES * HIDDEN * sizeof(float), stream);
  k_edge<<<N_EDGES / EBM, 256, 0, stream>>>(x, ei, ea, W1, b1, out);
  k_node<<<(N_NODES + NBM - 1) / NBM, 256, 0, stream>>>(x, out, W2, b2, out);
}